// Round 2
// baseline (325.892 us; speedup 1.0000x reference)
//
#include <hip/hip_runtime.h>
#include <hip/hip_bf16.h>

// EmbeddingBag mode='sum':
//   W       : [1e6, 64] float32
//   indices : [819200] int32
//   offsets : [16384] int32 (bag starts; last bag ends at n_idx)
//   out     : [16384, 64] float32,  out[b] = sum_{i in bag b} W[indices[i]]
//
// Layout: one wave per bag. 16 lanes per row, float4 per lane -> each
// global_load_dwordx4 wave-instruction gathers 4 ROWS (1 KB). Unroll 4
// groups (16 rows, 4 KB in flight, 4 independent accumulators) to cover
// ~900-cycle random-HBM latency. slot = lane>>4 (which of 4 rows),
// cg = lane&15 (which float4 column group).

#define EMB 64

__global__ __launch_bounds__(256) void embag_sum_kernel(
    const float* __restrict__ W,
    const int* __restrict__ indices,
    const int* __restrict__ offsets,
    float* __restrict__ out,
    int n_bags, int n_idx)
{
    const int wave = (int)((blockIdx.x * blockDim.x + threadIdx.x) >> 6);
    const int lane = (int)(threadIdx.x & 63);
    if (wave >= n_bags) return;

    const int slot = lane >> 4;    // row within 4-row group
    const int cg   = lane & 15;    // column group (float4)

    const int start = offsets[wave];
    const int end   = (wave + 1 < n_bags) ? offsets[wave + 1] : n_idx;

    float4 acc0 = {0.f,0.f,0.f,0.f}, acc1 = {0.f,0.f,0.f,0.f};
    float4 acc2 = {0.f,0.f,0.f,0.f}, acc3 = {0.f,0.f,0.f,0.f};

    for (int base = start; base < end; base += 64) {
        const int rem = end - base;
        const int cnt = rem < 64 ? rem : 64;
        // one coalesced load of up to 64 indices for this chunk
        const int myIdx = (lane < cnt) ? indices[base + lane] : 0;

        for (int k = 0; k < cnt; k += 16) {
            // 4 independent groups of 4 rows each -> 4 loads in flight
            const int r0 = k      + slot;
            const int r1 = k + 4  + slot;
            const int r2 = k + 8  + slot;
            const int r3 = k + 12 + slot;
            // rows are always < 64 (k<=48, slot<=3) so shfl src is valid;
            // padded lanes carry idx 0 (safe to load, masked on accumulate)
            const unsigned i0 = (unsigned)__shfl(myIdx, r0, 64);
            const unsigned i1 = (unsigned)__shfl(myIdx, r1, 64);
            const unsigned i2 = (unsigned)__shfl(myIdx, r2, 64);
            const unsigned i3 = (unsigned)__shfl(myIdx, r3, 64);

            const float4 v0 = *(const float4*)(W + (size_t)i0 * EMB + cg * 4);
            const float4 v1 = *(const float4*)(W + (size_t)i1 * EMB + cg * 4);
            const float4 v2 = *(const float4*)(W + (size_t)i2 * EMB + cg * 4);
            const float4 v3 = *(const float4*)(W + (size_t)i3 * EMB + cg * 4);

            if (r0 < cnt) { acc0.x += v0.x; acc0.y += v0.y; acc0.z += v0.z; acc0.w += v0.w; }
            if (r1 < cnt) { acc1.x += v1.x; acc1.y += v1.y; acc1.z += v1.z; acc1.w += v1.w; }
            if (r2 < cnt) { acc2.x += v2.x; acc2.y += v2.y; acc2.z += v2.z; acc2.w += v2.w; }
            if (r3 < cnt) { acc3.x += v3.x; acc3.y += v3.y; acc3.z += v3.z; acc3.w += v3.w; }
        }
    }

    float4 acc;
    acc.x = (acc0.x + acc1.x) + (acc2.x + acc3.x);
    acc.y = (acc0.y + acc1.y) + (acc2.y + acc3.y);
    acc.z = (acc0.z + acc1.z) + (acc2.z + acc3.z);
    acc.w = (acc0.w + acc1.w) + (acc2.w + acc3.w);

    // reduce across the 4 row-slots: butterfly over lane bits 4,5
    acc.x += __shfl_xor(acc.x, 16, 64);
    acc.y += __shfl_xor(acc.y, 16, 64);
    acc.z += __shfl_xor(acc.z, 16, 64);
    acc.w += __shfl_xor(acc.w, 16, 64);
    acc.x += __shfl_xor(acc.x, 32, 64);
    acc.y += __shfl_xor(acc.y, 32, 64);
    acc.z += __shfl_xor(acc.z, 32, 64);
    acc.w += __shfl_xor(acc.w, 32, 64);

    if (lane < 16) {
        *(float4*)(out + (size_t)wave * EMB + lane * 4) = acc;
    }
}

extern "C" void kernel_launch(void* const* d_in, const int* in_sizes, int n_in,
                              void* d_out, int out_size, void* d_ws, size_t ws_size,
                              hipStream_t stream) {
    const float* W        = (const float*)d_in[0];
    const int*   indices  = (const int*)d_in[1];
    const int*   offsets  = (const int*)d_in[2];
    float*       out      = (float*)d_out;

    const int n_idx  = in_sizes[1];
    const int n_bags = in_sizes[2];

    const int waves_per_block = 256 / 64;
    const int n_blocks = (n_bags + waves_per_block - 1) / waves_per_block;

    embag_sum_kernel<<<n_blocks, 256, 0, stream>>>(W, indices, offsets, out,
                                                   n_bags, n_idx);
}